// Round 16
// baseline (2160.860 us; speedup 1.0000x reference)
//
#include <hip/hip_runtime.h>

typedef float f32x4 __attribute__((ext_vector_type(4)));
typedef _Float16 f16x8 __attribute__((ext_vector_type(8)));
typedef _Float16 f16x4 __attribute__((ext_vector_type(4)));
typedef unsigned int u32x4 __attribute__((ext_vector_type(4)));

typedef const __attribute__((address_space(1))) unsigned int* gptr_t;
typedef __attribute__((address_space(3))) unsigned int* lptr_t;

__device__ __forceinline__ unsigned short f2h_u(float f){
  union { _Float16 h; unsigned short u; } cv; cv.h = (_Float16)f; return cv.u;
}
__device__ __forceinline__ float h2f(unsigned short u){
  union { unsigned short u; _Float16 h; } cv; cv.u = u; return (float)cv.h;
}
__device__ __forceinline__ float sigmoidf_(float x){ return 1.0f / (1.0f + __expf(-x)); }
__device__ __forceinline__ unsigned umax_(unsigned a, unsigned b){ return a > b ? a : b; }

// gemmz part slab indexing
#define GP(w,b,sp) ((((w)*64 + (b))<<6) + ((sp)<<2))

// ---- recurrence h loads: producer p = 16*wave + 4*c + q holds 8 cols ----
// piece mt: one 16B dwordx4 = full f16x8 B-fragment row
#define ISSUE16(DST, c)                                                        \
  _Pragma("unroll")                                                            \
  for (int mt = 0; mt < 4; ++mt){                                              \
    const unsigned short* a_ = hb2 +                                           \
        (size_t)(pb + (c) * 4) * 512 + (size_t)(mt * 16 + r) * 8;              \
    asm volatile("global_load_dwordx4 %0, %1, off sc0 sc1"                     \
                 : "=v"(DST[mt]) : "v"(a_) : "memory");                        \
  }

#define WAITVAL16(DST, c)                                                      \
  for (;;){                                                                    \
    asm volatile("s_waitcnt vmcnt(0)" ::: "memory");                           \
    __builtin_amdgcn_sched_barrier(0);                                         \
    unsigned mx_ = 0;                                                          \
    _Pragma("unroll")                                                          \
    for (int mt = 0; mt < 4; ++mt)                                             \
      mx_ = umax_(mx_, umax_(umax_(DST[mt][0], DST[mt][1]),                    \
                             umax_(DST[mt][2], DST[mt][3])));                  \
    if (__all(mx_ != 0xFFFFFFFFu)) break;                                      \
    ISSUE16(DST, c);                                                           \
  }

#define COMP16(DST, c)                                                         \
  _Pragma("unroll")                                                            \
  for (int nt = 0; nt < 4; ++nt)                                               \
    _Pragma("unroll")                                                          \
    for (int mt = 0; mt < 4; ++mt)                                             \
      acc[nt][mt] = __builtin_amdgcn_mfma_f32_16x16x32_f16(                    \
          uf[nt][(c)], *(const f16x8*)&DST[mt], acc[nt][mt], 0, 0, 0);

// ---------- conversion: x (B,S,I) f32 -> (S,B,I) f16 ----------
__global__ __launch_bounds__(256) void cvt_x(const float* __restrict__ in,
                                             unsigned short* __restrict__ out){
  int idx = blockIdx.x * 256 + threadIdx.x;
  int d4 = idx * 4;
  int s = d4 >> 16, b = (d4 >> 10) & 63, k = d4 & 1023;
  const float4 v = *(const float4*)(in + (size_t)b * 262144 + (size_t)s * 1024 + k);
  ushort4 o;
  o.x = f2h_u(v.x); o.y = f2h_u(v.y); o.z = f2h_u(v.z); o.w = f2h_u(v.w);
  *(ushort4*)(out + d4) = o;
}

struct P8 { const float* p[8]; };

__global__ __launch_bounds__(256) void cvt_w8(P8 mats, unsigned short* __restrict__ out){
  int idx = blockIdx.x * 256 + threadIdx.x;
  int e = idx * 4;
  int mi = e >> 20, off = e & 1048575;
  const float4 v = *(const float4*)(mats.p[mi] + off);
  ushort4 o;
  o.x = f2h_u(v.x); o.y = f2h_u(v.y); o.z = f2h_u(v.z); o.w = f2h_u(v.w);
  *(ushort4*)(out + e) = o;
}

__global__ __launch_bounds__(256) void pack8(P8 mats, unsigned short* __restrict__ out){
  int idx = blockIdx.x * 256 + threadIdx.x;
  int e = idx * 4;
  int j = e >> 10, k = e & 1023;
  int m = j & 7, row = j >> 3;
  const float4 v = *(const float4*)(mats.p[m] + (size_t)row * 1024 + k);
  ushort4 o;
  o.x = f2h_u(v.x); o.y = f2h_u(v.y); o.z = f2h_u(v.z); o.w = f2h_u(v.w);
  *(ushort4*)(out + e) = o;
}

// ---------- m97-style dual-B masked-linear GEMM (round-14 validated) ----------
__global__ __launch_bounds__(256, 2) void gemmz(
    const unsigned short* __restrict__ Xh,
    const unsigned short* __restrict__ Wg,
    unsigned short* __restrict__ Z01,
    unsigned short* __restrict__ Z23){
  __shared__ unsigned short As[128 * 32];
  __shared__ unsigned short Bl[128 * 32];
  __shared__ unsigned short Bm[128 * 32];
  const int tid = threadIdx.x;
  const int wave = tid >> 6, lane = tid & 63;
  const int r = lane & 15, q = lane >> 4;
  const int bid0 = blockIdx.x;
  const int bid = (bid0 & 7) * 512 + (bid0 >> 3);
  const int m0 = (bid & 127) * 128;
  const int n0 = ((bid >> 7) & 7) * 128;
  const int g  = bid >> 10;
  const int wm = wave >> 1, wn = wave & 1;

  const unsigned short* WL = Wg + ((size_t)(2 * g) << 20);
  const unsigned short* WM = WL + (1u << 20);

  f32x4 accL[4][4], accM[4][4];
#pragma unroll
  for (int a = 0; a < 4; ++a)
#pragma unroll
    for (int b = 0; b < 4; ++b){ accL[a][b] = 0.f; accM[a][b] = 0.f; }

  const int st_rl = lane >> 2;
  const int st_s0 = lane & 3;

  for (int kt = 0; kt < 32; ++kt){
    const int k0 = kt * 32;
#pragma unroll
    for (int j = 0; j < 2; ++j){
      const int c = wave * 2 + j;
      const int row = c * 16 + st_rl;
      const int slot = st_s0 ^ ((row >> 1) & 3);
      const unsigned short* sA = Xh + (size_t)(m0 + row) * 1024 + k0 + slot * 8;
      const unsigned short* sL = WL + (size_t)(n0 + row) * 1024 + k0 + slot * 8;
      const unsigned short* sM = WM + (size_t)(n0 + row) * 1024 + k0 + slot * 8;
      __builtin_amdgcn_global_load_lds((gptr_t)sA, (lptr_t)(As + c * 512), 16, 0, 0);
      __builtin_amdgcn_global_load_lds((gptr_t)sL, (lptr_t)(Bl + c * 512), 16, 0, 0);
      __builtin_amdgcn_global_load_lds((gptr_t)sM, (lptr_t)(Bm + c * 512), 16, 0, 0);
    }
    __syncthreads();

    f16x8 af[4], bl[4], bm[4];
#pragma unroll
    for (int mt = 0; mt < 4; ++mt){
      const int row = wm * 64 + mt * 16 + r;
      const int slot = q ^ ((row >> 1) & 3);
      af[mt] = *(const f16x8*)(As + row * 32 + slot * 8);
    }
#pragma unroll
    for (int nt = 0; nt < 4; ++nt){
      const int row = wn * 64 + nt * 16 + r;
      const int slot = q ^ ((row >> 1) & 3);
      bl[nt] = *(const f16x8*)(Bl + row * 32 + slot * 8);
      bm[nt] = *(const f16x8*)(Bm + row * 32 + slot * 8);
    }
#pragma unroll
    for (int nt = 0; nt < 4; ++nt)
#pragma unroll
      for (int mt = 0; mt < 4; ++mt){
        accL[mt][nt] = __builtin_amdgcn_mfma_f32_16x16x32_f16(af[mt], bl[nt], accL[mt][nt], 0, 0, 0);
        accM[mt][nt] = __builtin_amdgcn_mfma_f32_16x16x32_f16(af[mt], bm[nt], accM[mt][nt], 0, 0, 0);
      }
    __syncthreads();
  }

  unsigned short* Zp = (g < 2) ? (Z01 + ((size_t)g << 24)) : (Z23 + ((size_t)(g - 2) << 24));
#pragma unroll
  for (int mt = 0; mt < 4; ++mt)
#pragma unroll
    for (int nt = 0; nt < 4; ++nt){
      f32x4 aL = accL[mt][nt], aM = accM[mt][nt];
      union { ushort4 u; uint2 d; } o;
      o.u.x = f2h_u(aL[0] * sigmoidf_(aM[0]));
      o.u.y = f2h_u(aL[1] * sigmoidf_(aM[1]));
      o.u.z = f2h_u(aL[2] * sigmoidf_(aM[2]));
      o.u.w = f2h_u(aL[3] * sigmoidf_(aM[3]));
      const int gn = n0 + wn * 64 + nt * 16 + r;
      const int gm = m0 + wm * 64 + mt * 16 + q * 4;
      *(uint2*)(Zp + (size_t)gn * 16384 + gm) = o.d;
    }
}

// ---------- recurrence: 128 blocks x 512 thr, halved h broadcast ----------
// Block bi owns 8 cols (64 packed U rows, 4 n-tiles). Wave w (0..7): K-slice
// [w*128,+128) = producers [16w,16w+16). hh3[s][p=0..127][cb=0..63][8cols] f16,
// poisoned 0xFF; consumer 16B dwordx4 loads ARE the poll (poison-validate).
// part [8][64][68] f32, single-buffer, 2 syncs/step.
__global__ __launch_bounds__(512, 1) void lstm_rec(
    const unsigned short* __restrict__ zF, const unsigned short* __restrict__ zI,
    const unsigned short* __restrict__ zO, const unsigned short* __restrict__ zC,
    const unsigned short* __restrict__ Ug,
    const float* __restrict__ bF, const float* __restrict__ bI,
    const float* __restrict__ bO, const float* __restrict__ bC,
    unsigned short* __restrict__ hh3,        // [256][128][64][8] f16, poisoned
    float* __restrict__ out){
  const int tid = threadIdx.x, wave = tid >> 6, lane = tid & 63;
  const int bi = blockIdx.x, n0 = bi * 8, j0 = bi * 64;
  const int r = lane & 15, q = lane >> 4;
  const int pb = 16 * wave + q;            // producer base (chunk c adds 4c)
  extern __shared__ float part[];          // [8][64][68] = 139,264 B

  // resident weights: wave K-slice [wave*128,+128): 4 nt x 4 c frags = 64 VGPR
  f16x8 uf[4][4];
#pragma unroll
  for (int nt = 0; nt < 4; ++nt)
#pragma unroll
    for (int c = 0; c < 4; ++c)
      uf[nt][c] = *(const f16x8*)(Ug + (size_t)(j0 + nt * 16 + r) * 1024 +
                                  wave * 128 + c * 32 + q * 8);

  const int cb = tid >> 3, cl = tid & 7;   // combine: thread owns (batch cb, col cl)
  const float bFv = bF[n0 + cl], bIv = bI[n0 + cl], bOv = bO[n0 + cl], bCv = bC[n0 + cl];
  const size_t zb = (size_t)(n0 + cl) * 16384 + cb;
  float c_reg = 0.f;

#pragma unroll 1
  for (int s = 0; s < 256; ++s){
    float zf = h2f(zF[zb + s * 64]);
    float zi = h2f(zI[zb + s * 64]);
    float zo = h2f(zO[zb + s * 64]);
    float zc = h2f(zC[zb + s * 64]);

    f32x4 acc[4][4];
#pragma unroll
    for (int nt = 0; nt < 4; ++nt)
#pragma unroll
      for (int mt = 0; mt < 4; ++mt) acc[nt][mt] = 0.f;

    if (s > 0){
      const unsigned short* hb2 = hh3 + (size_t)(s - 1) * 65536;
      u32x4 hA[4], hB[4];
      ISSUE16(hA, 0);
      WAITVAL16(hA, 0);
      ISSUE16(hB, 1);
      COMP16(hA, 0);
      WAITVAL16(hB, 1);
      ISSUE16(hA, 2);
      COMP16(hB, 1);
      WAITVAL16(hA, 2);
      ISSUE16(hB, 3);
      COMP16(hA, 2);
      WAITVAL16(hB, 3);
      COMP16(hB, 3);
    }

    // part[w][b][nl]: D row (n-local) = nt*16+q*4+rg, col (batch) = mt*16+r
#pragma unroll
    for (int nt = 0; nt < 4; ++nt)
#pragma unroll
      for (int mt = 0; mt < 4; ++mt)
        *(f32x4*)&part[wave * 4352 + (mt * 16 + r) * 68 + nt * 16 + q * 4] = acc[nt][mt];
    __syncthreads();

    f32x4 y0 = 0.f, y1 = 0.f;
#pragma unroll
    for (int w = 0; w < 8; ++w){
      y0 += *(const f32x4*)&part[w * 4352 + cb * 68 + cl * 8];
      y1 += *(const f32x4*)&part[w * 4352 + cb * 68 + cl * 8 + 4];
    }
    __syncthreads();   // part reuse next step (single buffer)

    float fg = sigmoidf_(zf + y0[0] * sigmoidf_(y0[1]) + bFv);
    float ig = sigmoidf_(zi + y0[2] * sigmoidf_(y0[3]) + bIv);
    float og = sigmoidf_(zo + y1[0] * sigmoidf_(y1[1]) + bOv);
    float cg = tanhf   (zc + y1[2] * sigmoidf_(y1[3]) + bCv);
    c_reg = cg * ig + fg * c_reg;
    float h = og * c_reg;

    // producer store: cl==0 packs 8 cols -> one dwordx4 (16B), write-through LLC
    float h1 = __shfl_down(h, 1), h2v = __shfl_down(h, 2), h3 = __shfl_down(h, 3),
          h4 = __shfl_down(h, 4), h5 = __shfl_down(h, 5), h6 = __shfl_down(h, 6),
          h7 = __shfl_down(h, 7);
    if (cl == 0){
      u32x4 pv;
      pv[0] = (unsigned)f2h_u(h)   | ((unsigned)f2h_u(h1) << 16);
      pv[1] = (unsigned)f2h_u(h2v) | ((unsigned)f2h_u(h3) << 16);
      pv[2] = (unsigned)f2h_u(h4)  | ((unsigned)f2h_u(h5) << 16);
      pv[3] = (unsigned)f2h_u(h6)  | ((unsigned)f2h_u(h7) << 16);
      const unsigned short* hw = hh3 + (size_t)s * 65536 + (size_t)bi * 512 + cb * 8;
      asm volatile("global_store_dwordx4 %0, %1, off sc0 sc1" :: "v"(hw), "v"(pv) : "memory");
    }
    if (s == 255){
      out[16777216 + cb * 1024 + n0 + cl] = h;
      out[16777216 + 65536 + cb * 1024 + n0 + cl] = c_reg;
    }
  }
}

// ---------- expand hh3 [s][p][cb][8] -> out (B,S,H f32) ----------
__global__ __launch_bounds__(256) void expand_out(const unsigned short* __restrict__ hh3,
                                                  float* __restrict__ out){
  int idx = blockIdx.x * 256 + threadIdx.x;      // 2,097,152 threads
  int s = idx >> 13, rem = idx & 8191;
  int p = rem >> 6, cb = rem & 63;
  const unsigned short* src = hh3 + (size_t)idx * 8;
  ushort4 a = *(const ushort4*)src;
  ushort4 c = *(const ushort4*)(src + 4);
  size_t o = ((size_t)cb * 256 + s) * 1024 + p * 8;
  float4 f0 = { h2f(a.x), h2f(a.y), h2f(a.z), h2f(a.w) };
  float4 f1 = { h2f(c.x), h2f(c.y), h2f(c.z), h2f(c.w) };
  *(float4*)(out + o) = f0;
  *(float4*)(out + o + 4) = f1;
}

// ---------- host launch ----------
extern "C" void kernel_launch(void* const* d_in, const int* in_sizes, int n_in,
                              void* d_out, int out_size, void* d_ws, size_t ws_size,
                              hipStream_t stream){
  (void)in_sizes; (void)n_in; (void)out_size; (void)ws_size;
  char* ws = (char*)d_ws;
  const float* bF = (const float*)d_in[17];
  const float* bI = (const float*)d_in[18];
  const float* bO = (const float*)d_in[19];
  const float* bC = (const float*)d_in[20];
  float* outp = (float*)d_out;
  P8 w8, u8;
  for (int m = 0; m < 8; ++m){
    w8.p[m] = (const float*)d_in[1 + m];
    u8.p[m] = (const float*)d_in[9 + m];
  }

  unsigned short* xh  = (unsigned short*)(ws);               // 33,554,432 B
  unsigned short* wg  = (unsigned short*)(ws + 33554432);    // 16,777,216 B
  unsigned short* ug  = (unsigned short*)(ws + 50331648);    // 16,777,216 B
  unsigned short* z23 = (unsigned short*)(ws + 67108864);    // 67,108,864 B
  unsigned short* hh3 = (unsigned short*)(ws + 134217728);   // 33,554,432 B
  unsigned short* z01 = (unsigned short*)d_out;              // zT_f, zT_i

  (void)hipMemsetAsync(hh3, 0xFF, 33554432, stream);   // poison all h slots
  cvt_x<<<16384, 256, 0, stream>>>((const float*)d_in[0], xh);
  cvt_w8<<<8192, 256, 0, stream>>>(w8, wg);
  pack8<<<8192, 256, 0, stream>>>(u8, ug);
  gemmz<<<4096, 256, 0, stream>>>(xh, wg, z01, z23);

  const unsigned short* zF = z01;
  const unsigned short* zI = z01 + 16777216;
  const unsigned short* zO = z23;
  const unsigned short* zC = z23 + 16777216;

  void* args[] = { (void*)&zF, (void*)&zI, (void*)&zO, (void*)&zC, (void*)&ug,
                   (void*)&bF, (void*)&bI, (void*)&bO, (void*)&bC,
                   (void*)&hh3, (void*)&outp };
  size_t shmem = 8 * 64 * 68 * sizeof(float);   // 139,264 B
  if (hipLaunchCooperativeKernel((const void*)lstm_rec, dim3(128), dim3(512),
                                 args, (unsigned)shmem, stream) != hipSuccess)
    lstm_rec<<<128, 512, shmem, stream>>>(zF, zI, zO, zC, ug, bF, bI, bO, bC, hh3, outp);

  expand_out<<<8192, 256, 0, stream>>>(hh3, outp);
}